// Round 6
// baseline (165739.124 us; speedup 1.0000x reference)
//
#include <hip/hip_runtime.h>
#include <hip/hip_cooperative_groups.h>

constexpr int   NROWS = 65536;
constexpr int   NK    = 1024;
constexpr float PAv   = 1.0f / 65536.0f;
constexpr float PBv   = 1.0f / 1024.0f;
constexpr float FI    = 1.0f / 1.1f;          // GAMMA/(GAMMA+eps)
constexpr float NEG_INV_EPS = -10.0f;         // -1/eps
constexpr float STOPERR2 = 1e-12f;            // (1e-6)^2 on squared 2-norm
constexpr int   MAXIT = 1000;

// ---------------- cooperative Sinkhorn iteration ----------------
// Geometry: 256 blocks (1/CU; >1 block/CU coop launch REJECTED on HW, r2/3)
// x 512 threads. __launch_bounds__(512,2): 1 block resident, VGPR cap 256 so
// the ping-pong register double-buffer (2 x 16 float4) fits without spilling.
constexpr int IT_BLOCKS  = 256;
constexpr int IT_THREADS = 512;
constexpr int IT_WAVES   = IT_THREADS / 64;                 // 8
constexpr int IT_RPW     = NROWS / (IT_BLOCKS * IT_WAVES);  // 32 rows per wave
constexpr int NGRP       = 8;                               // atomic contention split

// load 4 rows (16 float4) into DST
#define SSK_LOAD(DST, RBASE)                                                  \
  {                                                                           \
    _Pragma("unroll")                                                         \
    for (int rr = 0; rr < 4; ++rr) {                                          \
      const float4* rp_ = reinterpret_cast<const float4*>(P)                  \
                        + (size_t)((RBASE) + rr) * (NK / 4);                  \
      _Pragma("unroll")                                                       \
      for (int k = 0; k < 4; ++k) DST[rr][k] = rp_[(k << 6) + lane];          \
    }                                                                         \
  }

// exp in place, 4 interleaved dot chains, butterfly reduce, a-scale, acc
#define SSK_COMPUTE(SRC)                                                      \
  {                                                                           \
    _Pragma("unroll")                                                         \
    for (int rr = 0; rr < 4; ++rr) {                                          \
      _Pragma("unroll")                                                       \
      for (int k = 0; k < 4; ++k) {                                           \
        SRC[rr][k].x = __expf(SRC[rr][k].x * NEG_INV_EPS);                    \
        SRC[rr][k].y = __expf(SRC[rr][k].y * NEG_INV_EPS);                    \
        SRC[rr][k].z = __expf(SRC[rr][k].z * NEG_INV_EPS);                    \
        SRC[rr][k].w = __expf(SRC[rr][k].w * NEG_INV_EPS);                    \
      }                                                                       \
    }                                                                         \
    float d_[4];                                                              \
    _Pragma("unroll")                                                         \
    for (int rr = 0; rr < 4; ++rr) {                                          \
      float dd = 0.f;                                                         \
      _Pragma("unroll")                                                       \
      for (int k = 0; k < 4; ++k) {                                           \
        dd = fmaf(SRC[rr][k].x, bb[4*k+0], dd);                               \
        dd = fmaf(SRC[rr][k].y, bb[4*k+1], dd);                               \
        dd = fmaf(SRC[rr][k].z, bb[4*k+2], dd);                               \
        dd = fmaf(SRC[rr][k].w, bb[4*k+3], dd);                               \
      }                                                                       \
      d_[rr] = dd;                                                            \
    }                                                                         \
    _Pragma("unroll")                                                         \
    for (int off = 32; off; off >>= 1) {                                      \
      _Pragma("unroll")                                                       \
      for (int rr = 0; rr < 4; ++rr) d_[rr] += __shfl_xor(d_[rr], off);       \
    }                                                                         \
    _Pragma("unroll")                                                         \
    for (int rr = 0; rr < 4; ++rr) {                                          \
      const float a_ = PAv / fmaxf(d_[rr], 1e-12f);                           \
      _Pragma("unroll")                                                       \
      for (int k = 0; k < 4; ++k) {                                           \
        acc[4*k+0] = fmaf(a_, SRC[rr][k].x, acc[4*k+0]);                      \
        acc[4*k+1] = fmaf(a_, SRC[rr][k].y, acc[4*k+1]);                      \
        acc[4*k+2] = fmaf(a_, SRC[rr][k].z, acc[4*k+2]);                      \
        acc[4*k+3] = fmaf(a_, SRC[rr][k].w, acc[4*k+3]);                      \
      }                                                                       \
    }                                                                         \
  }

__global__ __launch_bounds__(IT_THREADS, 2)
void ssk_iter(const float* __restrict__ P, float* __restrict__ csp /*[4][NGRP][NK]*/,
              unsigned int* __restrict__ bar_ctr, float* __restrict__ b_out)
{
  __shared__ float b_lds[NK];
  __shared__ float wave_cs[IT_WAVES][NK];   // 32 KiB
  __shared__ float redsh[IT_WAVES];
  __shared__ float err_sh;

  const int tid  = threadIdx.x;
  const int wave = tid >> 6;
  const int lane = tid & 63;
  const int bid  = blockIdx.x;
  const int grp  = bid & (NGRP - 1);
  const int row0 = (bid * IT_WAVES + wave) * IT_RPW;

  b_lds[tid] = PBv; b_lds[tid + 512] = PBv;   // b0 = 1/K
  __syncthreads();

  int it = 0;
  for (;;) {
    float* __restrict__ cs_cur = csp + (size_t)(it & 3) * (NGRP * NK);
    // slice-zero buffer (it+2): this block zeros its own 4 columns in all 8
    // groups (4 KB total grid-wide, no cross-block line contention).
    // Hazard audit: last readers of that buffer (Phase B, iter it-2) finished
    // before their arrive at barrier#(it-1); we passed barrier#(it-1).
    if (tid < 32) {
      float* z = csp + (size_t)((it + 2) & 3) * (NGRP * NK);
      const int g = tid >> 2, j = bid * 4 + (tid & 3);
      __hip_atomic_store(&z[g * NK + j], 0.0f, __ATOMIC_RELAXED,
                         __HIP_MEMORY_SCOPE_AGENT);
    }

    // lane's 16 columns: 256*k + 4*lane + j  (proven layout, 0 LDS conflicts)
    float bb[16];
    #pragma unroll
    for (int k = 0; k < 4; ++k)
      #pragma unroll
      for (int j = 0; j < 4; ++j)
        bb[4 * k + j] = b_lds[256 * k + 4 * lane + j];

    float acc[16];
    #pragma unroll
    for (int t = 0; t < 16; ++t) acc[t] = 0.0f;

    // ping-pong register double-buffer; sched_barrier(0) fences keep 16-32
    // loads in flight (16-32 KB/wave) instead of compiler-serialized pairs
    float4 A[4][4], B[4][4];
    SSK_LOAD(A, row0);
    #pragma unroll
    for (int r = 0; r < IT_RPW; r += 8) {
      SSK_LOAD(B, row0 + r + 4);
      __builtin_amdgcn_sched_barrier(0);
      SSK_COMPUTE(A);
      if (r + 8 < IT_RPW) { SSK_LOAD(A, row0 + r + 8); }
      __builtin_amdgcn_sched_barrier(0);
      SSK_COMPUTE(B);
    }

    // block-level column reduction, one atomic per column per block into the
    // block's contention group (32 blocks/group instead of 256/address)
    #pragma unroll
    for (int k = 0; k < 4; ++k)
      #pragma unroll
      for (int j = 0; j < 4; ++j)
        wave_cs[wave][256 * k + 4 * lane + j] = acc[4 * k + j];
    __syncthreads();
    #pragma unroll
    for (int h = 0; h < 2; ++h) {
      const int c = tid + 512 * h;
      float s = 0.f;
      #pragma unroll
      for (int w = 0; w < IT_WAVES; ++w) s += wave_cs[w][c];
      __hip_atomic_fetch_add(&cs_cur[grp * NK + c], s, __ATOMIC_RELAXED,
                             __HIP_MEMORY_SCOPE_AGENT);
    }

    // ---- lightweight grid barrier: monotonic counter, no cache-flush ----
    __threadfence();     // prior stores/atomics visible agent-wide
    __syncthreads();     // whole block done (incl. its atomics)
    if (tid == 0) {
      __hip_atomic_fetch_add(bar_ctr, 1u, __ATOMIC_RELEASE,
                             __HIP_MEMORY_SCOPE_AGENT);
      const unsigned int target = (unsigned int)(it + 1) * IT_BLOCKS;
      while (__hip_atomic_load(bar_ctr, __ATOMIC_ACQUIRE,
                               __HIP_MEMORY_SCOPE_AGENT) < target)
        __builtin_amdgcn_s_sleep(1);
    }
    __syncthreads();

    // Phase B: every block redundantly (bit-identically) computes b_new + err
    float c0 = 0.f, c1 = 0.f;
    #pragma unroll
    for (int g = 0; g < NGRP; ++g) {
      c0 += __hip_atomic_load(&cs_cur[g * NK + tid], __ATOMIC_RELAXED,
                              __HIP_MEMORY_SCOPE_AGENT);
      c1 += __hip_atomic_load(&cs_cur[g * NK + tid + 512], __ATOMIC_RELAXED,
                              __HIP_MEMORY_SCOPE_AGENT);
    }
    const float bn0 = powf(PBv / fmaxf(c0, 1e-12f), FI);
    const float bn1 = powf(PBv / fmaxf(c1, 1e-12f), FI);
    const float e0 = bn0 - b_lds[tid], e1 = bn1 - b_lds[tid + 512];
    float sq = e0 * e0 + e1 * e1;
    #pragma unroll
    for (int off = 32; off; off >>= 1) sq += __shfl_xor(sq, off);
    if (lane == 0) redsh[wave] = sq;
    __syncthreads();
    if (tid == 0) {
      float s = 0.f;
      #pragma unroll
      for (int w = 0; w < IT_WAVES; ++w) s += redsh[w];
      err_sh = s;
    }
    b_lds[tid] = bn0; b_lds[tid + 512] = bn1;  // own-index write
    ++it;
    __syncthreads();     // publishes err_sh and b_lds
    if (err_sh <= STOPERR2 || it >= MAXIT) break;
  }

  if (blockIdx.x == 0) { b_out[tid] = b_lds[tid]; b_out[tid + 512] = b_lds[tid + 512]; }
}

// ---------------- finalize: OT_plan + partial reductions (proven) ----------
constexpr int FN_BLOCKS  = 2048;
constexpr int FN_THREADS = 256;
constexpr int FN_WAVES   = FN_THREADS / 64;                  // 4
constexpr int FN_RPW     = NROWS / (FN_BLOCKS * FN_WAVES);   // 8

__global__ __launch_bounds__(FN_THREADS)
void ssk_finalize_kernel(const float* __restrict__ P, const float* __restrict__ b_glob,
                         float* __restrict__ out, float* __restrict__ wsum,
                         float* __restrict__ loss_part)
{
  __shared__ float b_sh[NK];
  __shared__ float wave_w[FN_WAVES][NK];
  __shared__ float red[FN_WAVES];

  const int tid  = threadIdx.x;
  const int wave = tid >> 6;
  const int lane = tid & 63;

  #pragma unroll
  for (int i = 0; i < 4; ++i) b_sh[tid + 256 * i] = b_glob[tid + 256 * i];
  __syncthreads();

  float bb[16];
  #pragma unroll
  for (int k = 0; k < 4; ++k)
    #pragma unroll
    for (int j = 0; j < 4; ++j)
      bb[4 * k + j] = b_sh[256 * k + 4 * lane + j];

  float wacc[16];
  #pragma unroll
  for (int t = 0; t < 16; ++t) wacc[t] = 0.0f;
  float lacc = 0.0f;

  const int row0 = (blockIdx.x * FN_WAVES + wave) * FN_RPW;
  float4* out4 = reinterpret_cast<float4*>(out);

  for (int r = 0; r < FN_RPW; ++r) {
    const size_t row = (size_t)(row0 + r);
    const float4* rp = reinterpret_cast<const float4*>(P) + row * (NK / 4);
    float4 pv[4];
    float Q[16];
    float dot = 0.0f;
    #pragma unroll
    for (int k = 0; k < 4; ++k) {
      pv[k] = rp[(k << 6) + lane];
      Q[4*k+0] = __expf(pv[k].x * NEG_INV_EPS);
      Q[4*k+1] = __expf(pv[k].y * NEG_INV_EPS);
      Q[4*k+2] = __expf(pv[k].z * NEG_INV_EPS);
      Q[4*k+3] = __expf(pv[k].w * NEG_INV_EPS);
      dot = fmaf(Q[4*k+0], bb[4*k+0], dot);
      dot = fmaf(Q[4*k+1], bb[4*k+1], dot);
      dot = fmaf(Q[4*k+2], bb[4*k+2], dot);
      dot = fmaf(Q[4*k+3], bb[4*k+3], dot);
    }
    #pragma unroll
    for (int off = 32; off; off >>= 1) dot += __shfl_xor(dot, off);
    const float s = 1.0f / fmaxf(dot, 1e-12f);    // N * a_i  (N*Pa = 1)
    #pragma unroll
    for (int k = 0; k < 4; ++k) {
      float4 o;
      o.x = s * Q[4*k+0] * bb[4*k+0];
      o.y = s * Q[4*k+1] * bb[4*k+1];
      o.z = s * Q[4*k+2] * bb[4*k+2];
      o.w = s * Q[4*k+3] * bb[4*k+3];
      out4[row * (NK / 4) + (k << 6) + lane] = o;
      lacc = fmaf(o.x, pv[k].x, lacc);
      lacc = fmaf(o.y, pv[k].y, lacc);
      lacc = fmaf(o.z, pv[k].z, lacc);
      lacc = fmaf(o.w, pv[k].w, lacc);
      wacc[4*k+0] += o.x; wacc[4*k+1] += o.y; wacc[4*k+2] += o.z; wacc[4*k+3] += o.w;
    }
  }

  #pragma unroll
  for (int k = 0; k < 4; ++k)
    #pragma unroll
    for (int j = 0; j < 4; ++j)
      wave_w[wave][256 * k + 4 * lane + j] = wacc[4 * k + j];
  __syncthreads();
  #pragma unroll
  for (int i = 0; i < 4; ++i) {
    const int c = tid + 256 * i;
    float s2 = wave_w[0][c] + wave_w[1][c] + wave_w[2][c] + wave_w[3][c];
    atomicAdd(&wsum[c], s2);
  }

  #pragma unroll
  for (int off = 32; off; off >>= 1) lacc += __shfl_xor(lacc, off);
  if (lane == 0) red[wave] = lacc;
  __syncthreads();
  if (tid == 0) loss_part[blockIdx.x] = red[0] + red[1] + red[2] + red[3];
}

// ---------------- finish: scalars ----------------
__device__ __forceinline__ float ssk_block_sum_1024(float v, float* red, int wave, int lane)
{
  #pragma unroll
  for (int off = 32; off; off >>= 1) v += __shfl_xor(v, off);
  __syncthreads();
  if (lane == 0) red[wave] = v;
  __syncthreads();
  float t = 0.0f;
  #pragma unroll
  for (int w = 0; w < 16; ++w) t += red[w];
  return t;
}

__global__ __launch_bounds__(1024)
void ssk_finish_kernel(const float* __restrict__ wsum, const float* __restrict__ loss_part,
                       float* __restrict__ out)
{
  __shared__ float red[16];
  const int tid = threadIdx.x, wave = tid >> 6, lane = tid & 63;

  float l  = loss_part[tid] + loss_part[tid + 1024];
  float lt = ssk_block_sum_1024(l, red, wave, lane);

  float wm = wsum[tid] * (1.0f / (float)NROWS);
  float sw = ssk_block_sum_1024(wm, red, wave, lane);
  float wn = wm / (sw + 1e-8f);
  float v  = PBv * (logf(PBv) - logf(wn + 1e-7f));
  float rg = ssk_block_sum_1024(v, red, wave, lane);

  if (tid == 0) {
    out[(size_t)NROWS * NK]     = lt / (float)NROWS;  // ot_loss
    out[(size_t)NROWS * NK + 1] = rg;                 // reg
  }
}

// ---------------- launch ----------------
extern "C" void kernel_launch(void* const* d_in, const int* in_sizes, int n_in,
                              void* d_out, int out_size, void* d_ws, size_t ws_size,
                              hipStream_t stream)
{
  const float* P = (const float*)d_in[0];
  float* out = (float*)d_out;
  float* ws  = (float*)d_ws;

  float*        csp       = ws;                              // [4][8][1024] = 128 KB
  unsigned int* bar_ctr   = (unsigned int*)(ws + 32768);     // own cache line
  float*        b_glob    = ws + 32784;                      // [1024]
  float*        wsum      = ws + 33808;                      // [1024]
  float*        loss_part = ws + 34832;                      // [2048]

  // zero ring + barrier counter + b_glob + wsum (deterministic across replays)
  hipMemsetAsync(ws, 0, 36880 * sizeof(float), stream);

  void* args[] = { (void*)&P, (void*)&csp, (void*)&bar_ctr, (void*)&b_glob };
  hipLaunchCooperativeKernel((void*)ssk_iter, dim3(IT_BLOCKS), dim3(IT_THREADS),
                             args, 0, stream);

  ssk_finalize_kernel<<<dim3(FN_BLOCKS), dim3(FN_THREADS), 0, stream>>>(
      P, b_glob, out, wsum, loss_part);
  ssk_finish_kernel<<<dim3(1), dim3(1024), 0, stream>>>(wsum, loss_part, out);
}

// Round 7
// 68429.175 us; speedup vs baseline: 2.4221x; 2.4221x over previous
//
#include <hip/hip_runtime.h>
#include <hip/hip_cooperative_groups.h>

namespace cg = cooperative_groups;

constexpr int   NROWS = 65536;
constexpr int   NK    = 1024;
constexpr float PAv   = 1.0f / 65536.0f;
constexpr float PBv   = 1.0f / 1024.0f;
constexpr float FI    = 1.0f / 1.1f;          // GAMMA/(GAMMA+eps)
constexpr float NEG_INV_EPS = -10.0f;         // -1/eps
constexpr float STOPERR2 = 1e-12f;            // (1e-6)^2 on squared 2-norm
constexpr int   MAXIT = 1000;
constexpr int   EXTRAP_EVERY = 64;            // Aitken cadence

// ---------------- cooperative Sinkhorn iteration ----------------
// Geometry: 256 blocks (1/CU; >1 block/CU coop launch REJECTED on HW, r2/3)
// x 512 threads; round-5 proven structure (131 us/iter, passed).
constexpr int IT_BLOCKS  = 256;
constexpr int IT_THREADS = 512;
constexpr int IT_WAVES   = IT_THREADS / 64;                 // 8
constexpr int IT_RPW     = NROWS / (IT_BLOCKS * IT_WAVES);  // 32 rows per wave

__global__ __launch_bounds__(IT_THREADS, 2)
void ssk_iter(const float* __restrict__ P, float* __restrict__ cs_ring,
              float* __restrict__ b_out)
{
  cg::grid_group grid = cg::this_grid();
  __shared__ float b_lds[NK];
  __shared__ float wave_cs[IT_WAVES][NK];   // 32 KiB
  __shared__ float redsh[IT_WAVES];
  __shared__ float err_sh;

  const int tid  = threadIdx.x;
  const int wave = tid >> 6;
  const int lane = tid & 63;
  const int row0 = (blockIdx.x * IT_WAVES + wave) * IT_RPW;

  b_lds[tid] = PBv; b_lds[tid + 512] = PBv;   // b0 = 1/K
  __syncthreads();

  float err_prev = 1.0f;
  int it = 0;
  for (;;) {
    float* __restrict__ cs_cur = cs_ring + (size_t)(it & 3) * NK;
    {
      // zero the buffer used 2 iters ahead; its last readers/writers (iter
      // it-2) finished before SYNC(it-1), which every block has passed.
      // Redundant zero-writes across blocks store the same value: benign.
      float* z = cs_ring + (size_t)((it + 2) & 3) * NK;
      z[tid] = 0.0f; z[tid + 512] = 0.0f;
    }

    // lane's 16 columns: 256*k + 4*lane + j  (proven layout, 0 LDS conflicts)
    float bb[16];
    #pragma unroll
    for (int k = 0; k < 4; ++k)
      #pragma unroll
      for (int j = 0; j < 4; ++j)
        bb[4 * k + j] = b_lds[256 * k + 4 * lane + j];

    float acc[16];
    #pragma unroll
    for (int t = 0; t < 16; ++t) acc[t] = 0.0f;

    for (int r = 0; r < IT_RPW; r += 8) {   // 8-row batch (round-5 proven)
      float4 v[8][4];
      #pragma unroll
      for (int rr = 0; rr < 8; ++rr) {
        const float4* rp = reinterpret_cast<const float4*>(P)
                         + (size_t)(row0 + r + rr) * (NK / 4);
        #pragma unroll
        for (int k = 0; k < 4; ++k) v[rr][k] = rp[(k << 6) + lane];
      }
      #pragma unroll
      for (int rr = 0; rr < 8; ++rr) {      // exp in place
        #pragma unroll
        for (int k = 0; k < 4; ++k) {
          v[rr][k].x = __expf(v[rr][k].x * NEG_INV_EPS);
          v[rr][k].y = __expf(v[rr][k].y * NEG_INV_EPS);
          v[rr][k].z = __expf(v[rr][k].z * NEG_INV_EPS);
          v[rr][k].w = __expf(v[rr][k].w * NEG_INV_EPS);
        }
      }
      float d[8];
      #pragma unroll
      for (int rr = 0; rr < 8; ++rr) {
        float dd = 0.f;
        #pragma unroll
        for (int k = 0; k < 4; ++k) {
          dd = fmaf(v[rr][k].x, bb[4*k+0], dd);
          dd = fmaf(v[rr][k].y, bb[4*k+1], dd);
          dd = fmaf(v[rr][k].z, bb[4*k+2], dd);
          dd = fmaf(v[rr][k].w, bb[4*k+3], dd);
        }
        d[rr] = dd;
      }
      #pragma unroll
      for (int off = 32; off; off >>= 1) {   // 8 interleaved butterfly chains
        #pragma unroll
        for (int rr = 0; rr < 8; ++rr) d[rr] += __shfl_xor(d[rr], off);
      }
      float aa[8];
      #pragma unroll
      for (int rr = 0; rr < 8; ++rr) aa[rr] = PAv / fmaxf(d[rr], 1e-12f);
      #pragma unroll
      for (int rr = 0; rr < 8; ++rr) {
        #pragma unroll
        for (int k = 0; k < 4; ++k) {
          acc[4*k+0] = fmaf(aa[rr], v[rr][k].x, acc[4*k+0]);
          acc[4*k+1] = fmaf(aa[rr], v[rr][k].y, acc[4*k+1]);
          acc[4*k+2] = fmaf(aa[rr], v[rr][k].z, acc[4*k+2]);
          acc[4*k+3] = fmaf(aa[rr], v[rr][k].w, acc[4*k+3]);
        }
      }
    }

    // block-level column reduction, one atomic per column per block
    #pragma unroll
    for (int k = 0; k < 4; ++k)
      #pragma unroll
      for (int j = 0; j < 4; ++j)
        wave_cs[wave][256 * k + 4 * lane + j] = acc[4 * k + j];
    __syncthreads();
    #pragma unroll
    for (int h = 0; h < 2; ++h) {
      const int c = tid + 512 * h;
      float s = 0.f;
      #pragma unroll
      for (int w = 0; w < IT_WAVES; ++w) s += wave_cs[w][c];
      atomicAdd(&cs_cur[c], s);
    }

    grid.sync();   // the only grid-wide sync per iteration

    // Phase B: every block redundantly (bit-identically) computes b_new + err
    const float c0 = cs_cur[tid], c1 = cs_cur[tid + 512];
    const float bn0 = powf(PBv / fmaxf(c0, 1e-12f), FI);
    const float bn1 = powf(PBv / fmaxf(c1, 1e-12f), FI);
    const float e0 = bn0 - b_lds[tid], e1 = bn1 - b_lds[tid + 512];
    float sq = e0 * e0 + e1 * e1;
    #pragma unroll
    for (int off = 32; off; off >>= 1) sq += __shfl_xor(sq, off);
    if (lane == 0) redsh[wave] = sq;
    __syncthreads();
    if (tid == 0) {
      float s = 0.f;
      #pragma unroll
      for (int w = 0; w < IT_WAVES; ++w) s += redsh[w];
      err_sh = s;
    }
    __syncthreads();           // publishes err_sh (b_lds not yet written)
    const float err = err_sh;  // uniform across grid (bit-identical reduction)
    ++it;
    const bool stop = (err <= STOPERR2) || (it >= MAXIT);

    // Aitken extrapolation every EXTRAP_EVERY plain iters: near the fixed
    // point delta_{t+1} ~ rho*delta_t (measured rho ~ 0.979), so jumping
    // b += delta * rho/(1-rho) removes the dominant mode. Safe: steps between
    // jumps are the exact reference map; stop requires a genuine residual
    // ||F(b)-b|| <= 1e-6; positivity floor + contraction repair overshoot.
    float fac = 0.0f;
    if (!stop && (it % EXTRAP_EVERY == 0)) {
      const float ratio = sqrtf(err / fmaxf(err_prev, 1e-30f));
      if (ratio > 0.5f && ratio < 0.9995f)
        fac = fminf(ratio / (1.0f - ratio), 300.0f);
    }
    float nb0 = bn0 + fac * e0; nb0 = fmaxf(nb0, 0.25f * bn0);
    float nb1 = bn1 + fac * e1; nb1 = fmaxf(nb1, 0.25f * bn1);
    b_lds[tid] = nb0; b_lds[tid + 512] = nb1;  // own-index write
    err_prev = err;
    __syncthreads();           // publishes b_lds for next iter
    if (stop) break;
  }

  if (blockIdx.x == 0) { b_out[tid] = b_lds[tid]; b_out[tid + 512] = b_lds[tid + 512]; }
}

// ---------------- finalize: OT_plan + partial reductions (proven) ----------
constexpr int FN_BLOCKS  = 2048;
constexpr int FN_THREADS = 256;
constexpr int FN_WAVES   = FN_THREADS / 64;                  // 4
constexpr int FN_RPW     = NROWS / (FN_BLOCKS * FN_WAVES);   // 8

__global__ __launch_bounds__(FN_THREADS)
void ssk_finalize_kernel(const float* __restrict__ P, const float* __restrict__ b_glob,
                         float* __restrict__ out, float* __restrict__ wsum,
                         float* __restrict__ loss_part)
{
  __shared__ float b_sh[NK];
  __shared__ float wave_w[FN_WAVES][NK];
  __shared__ float red[FN_WAVES];

  const int tid  = threadIdx.x;
  const int wave = tid >> 6;
  const int lane = tid & 63;

  #pragma unroll
  for (int i = 0; i < 4; ++i) b_sh[tid + 256 * i] = b_glob[tid + 256 * i];
  __syncthreads();

  float bb[16];
  #pragma unroll
  for (int k = 0; k < 4; ++k)
    #pragma unroll
    for (int j = 0; j < 4; ++j)
      bb[4 * k + j] = b_sh[256 * k + 4 * lane + j];

  float wacc[16];
  #pragma unroll
  for (int t = 0; t < 16; ++t) wacc[t] = 0.0f;
  float lacc = 0.0f;

  const int row0 = (blockIdx.x * FN_WAVES + wave) * FN_RPW;
  float4* out4 = reinterpret_cast<float4*>(out);

  for (int r = 0; r < FN_RPW; ++r) {
    const size_t row = (size_t)(row0 + r);
    const float4* rp = reinterpret_cast<const float4*>(P) + row * (NK / 4);
    float4 pv[4];
    float Q[16];
    float dot = 0.0f;
    #pragma unroll
    for (int k = 0; k < 4; ++k) {
      pv[k] = rp[(k << 6) + lane];
      Q[4*k+0] = __expf(pv[k].x * NEG_INV_EPS);
      Q[4*k+1] = __expf(pv[k].y * NEG_INV_EPS);
      Q[4*k+2] = __expf(pv[k].z * NEG_INV_EPS);
      Q[4*k+3] = __expf(pv[k].w * NEG_INV_EPS);
      dot = fmaf(Q[4*k+0], bb[4*k+0], dot);
      dot = fmaf(Q[4*k+1], bb[4*k+1], dot);
      dot = fmaf(Q[4*k+2], bb[4*k+2], dot);
      dot = fmaf(Q[4*k+3], bb[4*k+3], dot);
    }
    #pragma unroll
    for (int off = 32; off; off >>= 1) dot += __shfl_xor(dot, off);
    const float s = 1.0f / fmaxf(dot, 1e-12f);    // N * a_i  (N*Pa = 1)
    #pragma unroll
    for (int k = 0; k < 4; ++k) {
      float4 o;
      o.x = s * Q[4*k+0] * bb[4*k+0];
      o.y = s * Q[4*k+1] * bb[4*k+1];
      o.z = s * Q[4*k+2] * bb[4*k+2];
      o.w = s * Q[4*k+3] * bb[4*k+3];
      out4[row * (NK / 4) + (k << 6) + lane] = o;
      lacc = fmaf(o.x, pv[k].x, lacc);
      lacc = fmaf(o.y, pv[k].y, lacc);
      lacc = fmaf(o.z, pv[k].z, lacc);
      lacc = fmaf(o.w, pv[k].w, lacc);
      wacc[4*k+0] += o.x; wacc[4*k+1] += o.y; wacc[4*k+2] += o.z; wacc[4*k+3] += o.w;
    }
  }

  #pragma unroll
  for (int k = 0; k < 4; ++k)
    #pragma unroll
    for (int j = 0; j < 4; ++j)
      wave_w[wave][256 * k + 4 * lane + j] = wacc[4 * k + j];
  __syncthreads();
  #pragma unroll
  for (int i = 0; i < 4; ++i) {
    const int c = tid + 256 * i;
    float s2 = wave_w[0][c] + wave_w[1][c] + wave_w[2][c] + wave_w[3][c];
    atomicAdd(&wsum[c], s2);
  }

  #pragma unroll
  for (int off = 32; off; off >>= 1) lacc += __shfl_xor(lacc, off);
  if (lane == 0) red[wave] = lacc;
  __syncthreads();
  if (tid == 0) loss_part[blockIdx.x] = red[0] + red[1] + red[2] + red[3];
}

// ---------------- finish: scalars ----------------
__device__ __forceinline__ float ssk_block_sum_1024(float v, float* red, int wave, int lane)
{
  #pragma unroll
  for (int off = 32; off; off >>= 1) v += __shfl_xor(v, off);
  __syncthreads();
  if (lane == 0) red[wave] = v;
  __syncthreads();
  float t = 0.0f;
  #pragma unroll
  for (int w = 0; w < 16; ++w) t += red[w];
  return t;
}

__global__ __launch_bounds__(1024)
void ssk_finish_kernel(const float* __restrict__ wsum, const float* __restrict__ loss_part,
                       float* __restrict__ out)
{
  __shared__ float red[16];
  const int tid = threadIdx.x, wave = tid >> 6, lane = tid & 63;

  float l  = loss_part[tid] + loss_part[tid + 1024];
  float lt = ssk_block_sum_1024(l, red, wave, lane);

  float wm = wsum[tid] * (1.0f / (float)NROWS);
  float sw = ssk_block_sum_1024(wm, red, wave, lane);
  float wn = wm / (sw + 1e-8f);
  float v  = PBv * (logf(PBv) - logf(wn + 1e-7f));
  float rg = ssk_block_sum_1024(v, red, wave, lane);

  if (tid == 0) {
    out[(size_t)NROWS * NK]     = lt / (float)NROWS;  // ot_loss
    out[(size_t)NROWS * NK + 1] = rg;                 // reg
  }
}

// ---------------- launch ----------------
extern "C" void kernel_launch(void* const* d_in, const int* in_sizes, int n_in,
                              void* d_out, int out_size, void* d_ws, size_t ws_size,
                              hipStream_t stream)
{
  const float* P = (const float*)d_in[0];
  float* out = (float*)d_out;
  float* ws  = (float*)d_ws;

  float* cs_ring   = ws;             // [4][1024]
  float* b_glob    = ws + 4096;      // [1024]
  float* wsum      = ws + 5120;      // [1024]
  float* loss_part = ws + 6144;      // [2048]

  // zero ring + b_glob + wsum every call (deterministic across graph replays)
  hipMemsetAsync(ws, 0, 6144 * sizeof(float), stream);

  void* args[] = { (void*)&P, (void*)&cs_ring, (void*)&b_glob };
  hipLaunchCooperativeKernel((void*)ssk_iter, dim3(IT_BLOCKS), dim3(IT_THREADS),
                             args, 0, stream);

  ssk_finalize_kernel<<<dim3(FN_BLOCKS), dim3(FN_THREADS), 0, stream>>>(
      P, b_glob, out, wsum, loss_part);
  ssk_finish_kernel<<<dim3(1), dim3(1024), 0, stream>>>(wsum, loss_part, out);
}